// Round 20
// baseline (88.883 us; speedup 1.0000x reference)
//
#include <hip/hip_runtime.h>

// Problem constants (reference: shape (2,1,160,192,160), win=9)
#define BB 2
#define DD 160
#define HH 192
#define WW 160
#define HW (HH * WW)
#define PAD 4
#define TH 16
#define TW 16
#define EXT 24              // TH+2*PAD == TW+2*PAD
#define XSTR 28             // plane row stride (words; rows 16B-aligned)
#define PLANE 768           // words per array plane (>= EXT*XSTR=672)
#define SB_PAR (2 * PLANE)  // sbuf parity stride (x+y planes)
#define WCS 456             // wsum channel stride
#define WJS 28              // wsum j(col) stride (r contiguous, 16B-aligned)
#define WPS (5 * WCS)       // wsum parity stride (2280)
#define HWS 20              // hsum w stride (16 h + 4 pad; 4-aligned)
#define HCS2 324            // hsum channel stride (16*20+4; %4==0, %32==4)
#define HPS2 (5 * HCS2)     // hsum parity stride (1620)
#define CHUNK 55
#define NCH 3               // chunks: dc0 = 0,55,110 (last has 50 outputs)
#define NITER 63            // slices 0..62; CHUNK + 2*PAD = 7*9
#define WT (WW / TW)        // 10
#define HT (HH / TH)        // 12
#define NBLK (WT * HT * NCH * BB)  // 720
#define NTASK 288           // staging float4 tasks per slice (2 arr x 24 r x 6 q)
#define EPS 1e-5f
#define INV_WS (1.0f / 729.0f)

// barrier that waits LDS only — never drains vmcnt (keeps prefetch in flight)
__device__ __forceinline__ void bar_lgkm() {
  asm volatile("s_waitcnt lgkmcnt(0)" ::: "memory");
  __builtin_amdgcn_s_barrier();
  asm volatile("" ::: "memory");
}

__global__ void __launch_bounds__(256) k_lncc(
    const float* __restrict__ x, const float* __restrict__ y,
    float* __restrict__ partials, int* __restrict__ cnt,
    float* __restrict__ out)
{
  // Single-barrier pipeline; ALL LDS arrays parity-double-buffered (r19).
  // iter m: { store(m+1)->sbuf[(m+1)&1] ; prefetch(m+2) ;
  //           waves 0-1: P2(m): sbuf[m&1] -> wsum[m&1]
  //           waves 2-3: P3(m-1): wsum[(m-1)&1] -> hsum[(m-1)&1]
  //           all:       P4(m-2): reads hsum[(m-2)&1] ; ring ; cc } barrier
  __shared__ __align__(16) float sbuf[2 * SB_PAR];   // 12288 B [par][arr][..]
  __shared__ __align__(16) float wsum[2 * WPS];      // 18240 B [par][c][j][r]
  __shared__ __align__(16) float hsum[2 * HPS2];     // 12960 B [par][c][w][h]
  __shared__ double dred[256];                       // final-reduce scratch
  __shared__ float red[4];
  __shared__ int isLast;

  const int t = threadIdx.x;
  const int w0 = blockIdx.x * TW;
  const int h0 = blockIdx.y * TH;
  const int bz = blockIdx.z;
  const int b = bz / NCH;
  const int chunk = bz - b * NCH;
  const int dc0 = chunk * CHUNK;
  const int g0 = dc0 - PAD;

  // ---- init: zero both sbuf parities (OOB slots stay 0 forever) ----
  for (int i = t; i < 2 * SB_PAR; i += 256) sbuf[i] = 0.f;

  // ---- staging descriptors: NTASK float4 tasks; thread t gets t, 256+t ----
  int la0, la1; bool tk0, tk1;
  const float* gp0; const float* gp1;
  {
    const float* bx = x + (long)b * DD * HW;
    const float* by = y + (long)b * DD * HW;
#define MKTASK(TAU, LA, TK, GP)                                           \
    {                                                                     \
      int tau = (TAU);                                                    \
      int a = tau / 144;                                                  \
      int rem = tau - 144 * a;                                            \
      int r = rem / 6;                                                    \
      int q = rem - 6 * r;                                                \
      int aa = (a < 2) ? a : 0;                                           \
      int gh = h0 - PAD + r;                                              \
      int gw = w0 - PAD + 4 * q;                                          \
      bool ok = (tau < NTASK) && ((unsigned)gh < (unsigned)HH) &&         \
                ((unsigned)gw < (unsigned)WW);                            \
      LA = aa * PLANE + r * XSTR + 4 * q;                                 \
      TK = ok;                                                            \
      GP = (aa ? by : bx) + (ok ? (gh * WW + gw) : 0);                    \
    }
    MKTASK(t, la0, tk0, gp0)
    MKTASK(256 + t, la1, tk1, gp1)
#undef MKTASK
  }

  // ---- P2 constants (waves 0-1; task valid t<120): (channel c2, row r2) ----
  const int c2 = t / 24, r2 = t - c2 * 24;
  const int arrA = ((c2 == 1) || (c2 == 3)) ? 1 : 0;
  const bool needB = (c2 == 4);                 // only xy reads a second row
  const bool sqA = (c2 == 2) || (c2 == 3);
  const int paOff = arrA * PLANE + r2 * XSTR;   // + par*SB_PAR
  const int pbOff = PLANE + r2 * XSTR;          // y row (B of c4)
  const int wwOff = c2 * WCS + r2;              // + par*WPS + j*WJS

  // ---- P3 constants (waves 2-3; task tt=t-128 valid <80): (c3, w3) ----
  const int tt = t - 128;
  const int c3 = (tt >= 0 ? tt : 0) / 16, w3 = (tt >= 0 ? tt : 0) & 15;
  const int wrOff = c3 * WCS + w3 * WJS;        // + par*WPS, i contiguous
  const int hwOff = c3 * HCS2 + w3 * HWS;       // + par*HPS2, h contiguous

  // ---- P4 constants: one output (h,w) per thread ----
  const int h4 = t >> 4, w4 = t & 15;
  const int hrOff = w4 * HWS + h4;              // + par*HPS2 + c*HCS2

  // ---- D-window ring (static idx), running sums ----
  float ring[9][5];
#pragma unroll
  for (int i = 0; i < 9; ++i)
#pragma unroll
    for (int c = 0; c < 5; ++c) ring[i][c] = 0.f;
  float run0 = 0.f, run1 = 0.f, run2 = 0.f, run3 = 0.f, run4 = 0.f, acc = 0.f;

  __syncthreads();   // zero-init visible

// P2 body: reads A row (and B row only for c4) from sbuf[SBASE], writes
// wsum[WBASE] via sliding recurrence.
#define P2_BODY(SBASE, WBASE)                                              \
  {                                                                        \
    const float* pa = &sbuf[(SBASE) + paOff];                              \
    float4 A0 = *(const float4*)(pa);                                      \
    float4 A1 = *(const float4*)(pa + 4);                                  \
    float4 A2 = *(const float4*)(pa + 8);                                  \
    float4 A3 = *(const float4*)(pa + 12);                                 \
    float4 A4 = *(const float4*)(pa + 16);                                 \
    float4 A5 = *(const float4*)(pa + 20);                                 \
    float av[EXT];                                                         \
    av[0]=A0.x; av[1]=A0.y; av[2]=A0.z; av[3]=A0.w;                        \
    av[4]=A1.x; av[5]=A1.y; av[6]=A1.z; av[7]=A1.w;                        \
    av[8]=A2.x; av[9]=A2.y; av[10]=A2.z; av[11]=A2.w;                      \
    av[12]=A3.x; av[13]=A3.y; av[14]=A3.z; av[15]=A3.w;                    \
    av[16]=A4.x; av[17]=A4.y; av[18]=A4.z; av[19]=A4.w;                    \
    av[20]=A5.x; av[21]=A5.y; av[22]=A5.z; av[23]=A5.w;                    \
    float q[EXT];                                                          \
    if (needB) {                                                           \
      const float* pb = &sbuf[(SBASE) + pbOff];                            \
      float4 B0 = *(const float4*)(pb);                                    \
      float4 B1 = *(const float4*)(pb + 4);                                \
      float4 B2 = *(const float4*)(pb + 8);                                \
      float4 B3 = *(const float4*)(pb + 12);                               \
      float4 B4 = *(const float4*)(pb + 16);                               \
      float4 B5 = *(const float4*)(pb + 20);                               \
      q[0]=av[0]*B0.x; q[1]=av[1]*B0.y; q[2]=av[2]*B0.z; q[3]=av[3]*B0.w;  \
      q[4]=av[4]*B1.x; q[5]=av[5]*B1.y; q[6]=av[6]*B1.z; q[7]=av[7]*B1.w;  \
      q[8]=av[8]*B2.x; q[9]=av[9]*B2.y; q[10]=av[10]*B2.z;                 \
      q[11]=av[11]*B2.w;                                                   \
      q[12]=av[12]*B3.x; q[13]=av[13]*B3.y; q[14]=av[14]*B3.z;             \
      q[15]=av[15]*B3.w;                                                   \
      q[16]=av[16]*B4.x; q[17]=av[17]*B4.y; q[18]=av[18]*B4.z;             \
      q[19]=av[19]*B4.w;                                                   \
      q[20]=av[20]*B5.x; q[21]=av[21]*B5.y; q[22]=av[22]*B5.z;             \
      q[23]=av[23]*B5.w;                                                   \
    } else {                                                               \
      _Pragma("unroll")                                                    \
      for (int i = 0; i < EXT; ++i) q[i] = sqA ? av[i] * av[i] : av[i];    \
    }                                                                      \
    float s = ((q[0] + q[1]) + (q[2] + q[3])) +                            \
              ((q[4] + q[5]) + (q[6] + q[7])) + q[8];                      \
    float* wq = &wsum[(WBASE) + wwOff];                                    \
    wq[0] = s;                                                             \
    _Pragma("unroll")                                                      \
    for (int j = 1; j < TW; ++j) {                                         \
      s += q[j + 8] - q[j - 1];                                            \
      wq[j * WJS] = s;                                                     \
    }                                                                      \
  }

  // ---- prologue: store slice 0 -> sbuf[par 0]; prefetch slice 1 ----
  float4 st0 = make_float4(0, 0, 0, 0), st1 = st0;
  bool ps0 = false, ps1 = false;
  {
    if ((unsigned)g0 < (unsigned)DD) {
      const long so = (long)g0 * HW;
      if (tk0) *(float4*)&sbuf[la0] = *(const float4*)(gp0 + so);
      if (tk1) *(float4*)&sbuf[la1] = *(const float4*)(gp1 + so);
    }
    const int g1i = g0 + 1;
    const bool v1 = ((unsigned)g1i < (unsigned)DD);
    const long so1 = (long)g1i * HW;
    ps0 = tk0 && v1; if (ps0) st0 = *(const float4*)(gp0 + so1);
    ps1 = tk1 && v1; if (ps1) st1 = *(const float4*)(gp1 + so1);
  }
  __syncthreads();   // slice-0 stores visible for P2(0)

  // ---- main loop: m = 0..71 (slices + pipeline drain; dead iters inert) ----
  for (int ko = 0; ko < 8; ++ko) {
#pragma unroll
    for (int jj = 0; jj < 9; ++jj) {
      const int m = ko * 9 + jj;
      const int parm = m & 1;

      // ---- store slice m+1 -> sbuf[(m+1)&1] (ps from previous prefetch) ----
      {
        float* sb1 = &sbuf[(parm ^ 1) * SB_PAR];
        if (ps0) *(float4*)&sb1[la0] = st0;
        if (ps1) *(float4*)&sb1[la1] = st1;
      }
      // ---- prefetch slice m+2 (in flight across the barrier) ----
      {
        const int gn = g0 + m + 2;
        const bool nv = (m + 2 < NITER) && ((unsigned)gn < (unsigned)DD);
        const long so = (long)gn * HW;
        ps0 = tk0 && nv; if (ps0) st0 = *(const float4*)(gp0 + so);
        ps1 = tk1 && nv; if (ps1) st1 = *(const float4*)(gp1 + so);
      }

      // ---- P2(m) on waves 0-1  ||  P3(m-1) on waves 2-3 ----
      if (t < 128) {
        if ((m < NITER) && ((unsigned)(g0 + m) < (unsigned)DD) && (t < 120))
          P2_BODY(parm * SB_PAR, parm * WPS)
      } else {
        const int s3 = m - 1;
        if ((m >= 1) && (s3 < NITER) &&
            ((unsigned)(g0 + s3) < (unsigned)DD) && (tt < 80)) {
          const int p3 = s3 & 1;
          const float* wrd = &wsum[p3 * WPS + wrOff];
          float4 V0 = *(const float4*)(wrd);
          float4 V1 = *(const float4*)(wrd + 4);
          float4 V2 = *(const float4*)(wrd + 8);
          float4 V3 = *(const float4*)(wrd + 12);
          float4 V4 = *(const float4*)(wrd + 16);
          float4 V5 = *(const float4*)(wrd + 20);
          float v[EXT];
          v[0]=V0.x; v[1]=V0.y; v[2]=V0.z; v[3]=V0.w;
          v[4]=V1.x; v[5]=V1.y; v[6]=V1.z; v[7]=V1.w;
          v[8]=V2.x; v[9]=V2.y; v[10]=V2.z; v[11]=V2.w;
          v[12]=V3.x; v[13]=V3.y; v[14]=V3.z; v[15]=V3.w;
          v[16]=V4.x; v[17]=V4.y; v[18]=V4.z; v[19]=V4.w;
          v[20]=V5.x; v[21]=V5.y; v[22]=V5.z; v[23]=V5.w;
          float hv[TH];
          float sv = ((v[0] + v[1]) + (v[2] + v[3])) +
                     ((v[4] + v[5]) + (v[6] + v[7])) + v[8];
          hv[0] = sv;
#pragma unroll
          for (int h = 1; h < TH; ++h) {
            sv += v[h + 8] - v[h - 1];
            hv[h] = sv;
          }
          float* hq = &hsum[p3 * HPS2 + hwOff];
          *(float4*)&hq[0]  = make_float4(hv[0],  hv[1],  hv[2],  hv[3]);
          *(float4*)&hq[4]  = make_float4(hv[4],  hv[5],  hv[6],  hv[7]);
          *(float4*)&hq[8]  = make_float4(hv[8],  hv[9],  hv[10], hv[11]);
          *(float4*)&hq[12] = make_float4(hv[12], hv[13], hv[14], hv[15]);
        }
      }

      // ---- P4(m-2) on all threads: hsum[(m-2)&1] + ring + cc ----
      const int s4 = m - 2;
      float hv0 = 0.f, hv1 = 0.f, hv2 = 0.f, hv3 = 0.f, hv4 = 0.f;
      if ((m >= 2) && (s4 < NITER) && ((unsigned)(g0 + s4) < (unsigned)DD)) {
        const float* hb = &hsum[(s4 & 1) * HPS2 + hrOff];
        hv0 = hb[0];
        hv1 = hb[HCS2];
        hv2 = hb[2 * HCS2];
        hv3 = hb[3 * HCS2];
        hv4 = hb[4 * HCS2];
      }
      {
        const int rr = (jj + 7) % 9;     // == s4 % 9; compile-time per jj
        run0 += hv0 - ring[rr][0]; ring[rr][0] = hv0;
        run1 += hv1 - ring[rr][1]; ring[rr][1] = hv1;
        run2 += hv2 - ring[rr][2]; ring[rr][2] = hv2;
        run3 += hv3 - ring[rr][3]; ring[rr][3] = hv3;
        run4 += hv4 - ring[rr][4]; ring[rr][4] = hv4;
      }
      if ((s4 >= 8) && (s4 < NITER)) {
        const int d = dc0 + (s4 - 8);
        if (d < DD) {                    // block-uniform tail guard
          float cross = fmaf(-run0 * INV_WS, run1, run4);
          float xv = fmaxf(fmaf(-run0 * INV_WS, run0, run2), EPS);
          float yv = fmaxf(fmaf(-run1 * INV_WS, run1, run3), EPS);
          acc += (cross * cross) * __builtin_amdgcn_rcpf(xv * yv);
        }
      }

      bar_lgkm();   // single barrier per slice
    }
  }

  // ---- block reduction ----
#pragma unroll
  for (int o = 32; o > 0; o >>= 1) acc += __shfl_down(acc, o);
  if ((t & 63) == 0) red[t >> 6] = acc;
  __syncthreads();
  const int bid = (bz * HT + blockIdx.y) * WT + blockIdx.x;
  if (t == 0) {
    partials[bid] = (red[0] + red[1]) + (red[2] + red[3]);
    __threadfence();                       // release partials (device scope)
    int prev = atomicAdd(cnt, 1);
    isLast = (prev == NBLK - 1) ? 1 : 0;
  }
  __syncthreads();

  // ---- fused finalize: last block reduces all partials (deterministic) ----
  if (isLast) {
    __threadfence();                       // acquire partials
    double s = 0.0;
    for (int i = t; i < NBLK; i += 256) s += (double)partials[i];
    dred[t] = s;
    __syncthreads();
    for (int o = 128; o > 0; o >>= 1) {
      if (t < o) dred[t] += dred[t + o];
      __syncthreads();
    }
    if (t == 0) {
      const double Nvox = (double)BB * DD * HH * WW;
      out[0] = (float)(-dred[0] / Nvox);
    }
  }
}

extern "C" void kernel_launch(void* const* d_in, const int* in_sizes, int n_in,
                              void* d_out, int out_size, void* d_ws, size_t ws_size,
                              hipStream_t stream) {
  (void)in_sizes; (void)n_in; (void)out_size; (void)ws_size;
  const float* x = (const float*)d_in[0];
  const float* y = (const float*)d_in[1];
  float* out = (float*)d_out;
  float* partials = (float*)d_ws;
  int* cnt = (int*)((char*)d_ws + NBLK * sizeof(float));

  // zero the arrival counter each call (deterministic; graph-capturable)
  hipMemsetAsync(cnt, 0, sizeof(int), stream);

  dim3 grid(WT, HT, BB * NCH);
  k_lncc<<<grid, 256, 0, stream>>>(x, y, partials, cnt, out);
}

// Round 21
// 69.448 us; speedup vs baseline: 1.2799x; 1.2799x over previous
//
#include <hip/hip_runtime.h>

// Problem constants (reference: shape (2,1,160,192,160), win=9)
#define BB 2
#define DD 160
#define HH 192
#define WW 160
#define HW (HH * WW)
#define PAD 4
#define TH 16
#define TW 16
#define EXT 24              // TH+2*PAD == TW+2*PAD
#define XSTR 28             // plane row stride (words; rows 16B-aligned)
#define PLANE 768           // words per array plane (>= EXT*XSTR=672)
#define SB_PAR (2 * PLANE)  // sbuf parity stride (x+y planes)
#define WCS 456             // wsum channel stride
#define WJS 28              // wsum j(col) stride (r contiguous, 16B-aligned)
#define WPS (5 * WCS)       // wsum parity stride (2280)
#define HWS 20              // hsum w stride (16 h + 4 pad; 4-aligned)
#define HCS2 324            // hsum channel stride (16*20+4; %4==0, %32==4)
#define HPS2 (5 * HCS2)     // hsum parity stride (1620)
#define CHUNK 55
#define NCH 3               // chunks: dc0 = 0,55,110 (last has 50 outputs)
#define NITER 63            // slices 0..62; CHUNK + 2*PAD = 7*9
#define WT (WW / TW)        // 10
#define HT (HH / TH)        // 12
#define NBLK (WT * HT * NCH * BB)  // 720
#define NTASK 288           // staging float4 tasks per slice (2 arr x 24 r x 6 q)
#define EPS 1e-5f
#define INV_WS (1.0f / 729.0f)

// barrier that waits LDS only — never drains vmcnt (keeps prefetch in flight)
__device__ __forceinline__ void bar_lgkm() {
  asm volatile("s_waitcnt lgkmcnt(0)" ::: "memory");
  __builtin_amdgcn_s_barrier();
  asm volatile("" ::: "memory");
}

__global__ void __launch_bounds__(256) k_lncc(
    const float* __restrict__ x, const float* __restrict__ y,
    float* __restrict__ partials)
{
  // Single-barrier pipeline; ALL LDS arrays parity-double-buffered.
  // iter m: { store(m+1)->sbuf[(m+1)&1] ; prefetch(m+2) ;
  //           waves 0-1: P2(m): sbuf[m&1] -> wsum[m&1]
  //           waves 2-3: P3(m-1): wsum[(m-1)&1] -> hsum[(m-1)&1]
  //           all:       P4(m-2): reads hsum[(m-2)&1] ; ring ; cc } barrier
  // Hazards (all parity-disjoint in-interval, cross exactly 1 barrier):
  //  sbuf: store(m+1,par p') vs P2(m,par p): disjoint; P2(m+1) next iter.
  //  wsum: P2(m) writes par p; P3 reads par p at iter m+1 (1 barrier).
  //        P3(m-1) reads par p'; next write to p' is P2(m+1), next iter.
  //  hsum: P3(m-1) writes par p'; P4 reads par p' at iter m+1 (1 barrier).
  //        P4(m-2) reads par p; next P3 write to par p is iter m+2 (2 bars).
  __shared__ __align__(16) float sbuf[2 * SB_PAR];   // 12288 B [par][arr][..]
  __shared__ __align__(16) float wsum[2 * WPS];      // 18240 B [par][c][j][r]
  __shared__ __align__(16) float hsum[2 * HPS2];     // 12960 B [par][c][w][h]
  __shared__ float red[4];

  const int t = threadIdx.x;
  const int w0 = blockIdx.x * TW;
  const int h0 = blockIdx.y * TH;
  const int bz = blockIdx.z;
  const int b = bz / NCH;
  const int chunk = bz - b * NCH;
  const int dc0 = chunk * CHUNK;
  const int g0 = dc0 - PAD;

  // ---- init: zero both sbuf parities (OOB slots stay 0 forever) ----
  for (int i = t; i < 2 * SB_PAR; i += 256) sbuf[i] = 0.f;

  // ---- staging descriptors: NTASK float4 tasks; thread t gets t, 256+t ----
  int la0, la1; bool tk0, tk1;
  const float* gp0; const float* gp1;
  {
    const float* bx = x + (long)b * DD * HW;
    const float* by = y + (long)b * DD * HW;
#define MKTASK(TAU, LA, TK, GP)                                           \
    {                                                                     \
      int tau = (TAU);                                                    \
      int a = tau / 144;                                                  \
      int rem = tau - 144 * a;                                            \
      int r = rem / 6;                                                    \
      int q = rem - 6 * r;                                                \
      int aa = (a < 2) ? a : 0;                                           \
      int gh = h0 - PAD + r;                                              \
      int gw = w0 - PAD + 4 * q;                                          \
      bool ok = (tau < NTASK) && ((unsigned)gh < (unsigned)HH) &&         \
                ((unsigned)gw < (unsigned)WW);                            \
      LA = aa * PLANE + r * XSTR + 4 * q;                                 \
      TK = ok;                                                            \
      GP = (aa ? by : bx) + (ok ? (gh * WW + gw) : 0);                    \
    }
    MKTASK(t, la0, tk0, gp0)
    MKTASK(256 + t, la1, tk1, gp1)
#undef MKTASK
  }

  // ---- P2 constants (waves 0-1; task valid t<120): (channel c2, row r2) ----
  const int c2 = t / 24, r2 = t - c2 * 24;
  const int arrA = ((c2 == 1) || (c2 == 3)) ? 1 : 0;
  const bool needB = (c2 == 4);                 // only xy reads a second row
  const bool sqA = (c2 == 2) || (c2 == 3);
  const int paOff = arrA * PLANE + r2 * XSTR;   // + par*SB_PAR
  const int pbOff = PLANE + r2 * XSTR;          // y row (B of c4)
  const int wwOff = c2 * WCS + r2;              // + par*WPS + j*WJS

  // ---- P3 constants (waves 2-3; task tt=t-128 valid <80): (c3, w3) ----
  const int tt = t - 128;
  const int c3 = (tt >= 0 ? tt : 0) / 16, w3 = (tt >= 0 ? tt : 0) & 15;
  const int wrOff = c3 * WCS + w3 * WJS;        // + par*WPS, i contiguous
  const int hwOff = c3 * HCS2 + w3 * HWS;       // + par*HPS2, h contiguous

  // ---- P4 constants: one output (h,w) per thread ----
  const int h4 = t >> 4, w4 = t & 15;
  const int hrOff = w4 * HWS + h4;              // + par*HPS2 + c*HCS2

  // ---- D-window ring (static idx), running sums ----
  float ring[9][5];
#pragma unroll
  for (int i = 0; i < 9; ++i)
#pragma unroll
    for (int c = 0; c < 5; ++c) ring[i][c] = 0.f;
  float run0 = 0.f, run1 = 0.f, run2 = 0.f, run3 = 0.f, run4 = 0.f, acc = 0.f;

  __syncthreads();   // zero-init visible

// P2 body: reads A row (and B row only for c4) from sbuf[SBASE], writes
// wsum[WBASE] via sliding recurrence.
#define P2_BODY(SBASE, WBASE)                                              \
  {                                                                        \
    const float* pa = &sbuf[(SBASE) + paOff];                              \
    float4 A0 = *(const float4*)(pa);                                      \
    float4 A1 = *(const float4*)(pa + 4);                                  \
    float4 A2 = *(const float4*)(pa + 8);                                  \
    float4 A3 = *(const float4*)(pa + 12);                                 \
    float4 A4 = *(const float4*)(pa + 16);                                 \
    float4 A5 = *(const float4*)(pa + 20);                                 \
    float av[EXT];                                                         \
    av[0]=A0.x; av[1]=A0.y; av[2]=A0.z; av[3]=A0.w;                        \
    av[4]=A1.x; av[5]=A1.y; av[6]=A1.z; av[7]=A1.w;                        \
    av[8]=A2.x; av[9]=A2.y; av[10]=A2.z; av[11]=A2.w;                      \
    av[12]=A3.x; av[13]=A3.y; av[14]=A3.z; av[15]=A3.w;                    \
    av[16]=A4.x; av[17]=A4.y; av[18]=A4.z; av[19]=A4.w;                    \
    av[20]=A5.x; av[21]=A5.y; av[22]=A5.z; av[23]=A5.w;                    \
    float q[EXT];                                                          \
    if (needB) {                                                           \
      const float* pb = &sbuf[(SBASE) + pbOff];                            \
      float4 B0 = *(const float4*)(pb);                                    \
      float4 B1 = *(const float4*)(pb + 4);                                \
      float4 B2 = *(const float4*)(pb + 8);                                \
      float4 B3 = *(const float4*)(pb + 12);                               \
      float4 B4 = *(const float4*)(pb + 16);                               \
      float4 B5 = *(const float4*)(pb + 20);                               \
      q[0]=av[0]*B0.x; q[1]=av[1]*B0.y; q[2]=av[2]*B0.z; q[3]=av[3]*B0.w;  \
      q[4]=av[4]*B1.x; q[5]=av[5]*B1.y; q[6]=av[6]*B1.z; q[7]=av[7]*B1.w;  \
      q[8]=av[8]*B2.x; q[9]=av[9]*B2.y; q[10]=av[10]*B2.z;                 \
      q[11]=av[11]*B2.w;                                                   \
      q[12]=av[12]*B3.x; q[13]=av[13]*B3.y; q[14]=av[14]*B3.z;             \
      q[15]=av[15]*B3.w;                                                   \
      q[16]=av[16]*B4.x; q[17]=av[17]*B4.y; q[18]=av[18]*B4.z;             \
      q[19]=av[19]*B4.w;                                                   \
      q[20]=av[20]*B5.x; q[21]=av[21]*B5.y; q[22]=av[22]*B5.z;             \
      q[23]=av[23]*B5.w;                                                   \
    } else {                                                               \
      _Pragma("unroll")                                                    \
      for (int i = 0; i < EXT; ++i) q[i] = sqA ? av[i] * av[i] : av[i];    \
    }                                                                      \
    float s = ((q[0] + q[1]) + (q[2] + q[3])) +                            \
              ((q[4] + q[5]) + (q[6] + q[7])) + q[8];                      \
    float* wq = &wsum[(WBASE) + wwOff];                                    \
    wq[0] = s;                                                             \
    _Pragma("unroll")                                                      \
    for (int j = 1; j < TW; ++j) {                                         \
      s += q[j + 8] - q[j - 1];                                            \
      wq[j * WJS] = s;                                                     \
    }                                                                      \
  }

  // ---- prologue: store slice 0 -> sbuf[par 0]; prefetch slice 1 ----
  float4 st0 = make_float4(0, 0, 0, 0), st1 = st0;
  bool ps0 = false, ps1 = false;
  {
    if ((unsigned)g0 < (unsigned)DD) {
      const long so = (long)g0 * HW;
      if (tk0) *(float4*)&sbuf[la0] = *(const float4*)(gp0 + so);
      if (tk1) *(float4*)&sbuf[la1] = *(const float4*)(gp1 + so);
    }
    const int g1i = g0 + 1;
    const bool v1 = ((unsigned)g1i < (unsigned)DD);
    const long so1 = (long)g1i * HW;
    ps0 = tk0 && v1; if (ps0) st0 = *(const float4*)(gp0 + so1);
    ps1 = tk1 && v1; if (ps1) st1 = *(const float4*)(gp1 + so1);
  }
  __syncthreads();   // slice-0 stores visible for P2(0)

  // ---- main loop: m = 0..71 (slices + pipeline drain; dead iters inert) ----
  for (int ko = 0; ko < 8; ++ko) {
#pragma unroll
    for (int jj = 0; jj < 9; ++jj) {
      const int m = ko * 9 + jj;
      const int parm = m & 1;

      // ---- store slice m+1 -> sbuf[(m+1)&1] (ps from previous prefetch) ----
      {
        float* sb1 = &sbuf[(parm ^ 1) * SB_PAR];
        if (ps0) *(float4*)&sb1[la0] = st0;
        if (ps1) *(float4*)&sb1[la1] = st1;
      }
      // ---- prefetch slice m+2 (in flight across the barrier) ----
      {
        const int gn = g0 + m + 2;
        const bool nv = (m + 2 < NITER) && ((unsigned)gn < (unsigned)DD);
        const long so = (long)gn * HW;
        ps0 = tk0 && nv; if (ps0) st0 = *(const float4*)(gp0 + so);
        ps1 = tk1 && nv; if (ps1) st1 = *(const float4*)(gp1 + so);
      }

      // ---- P2(m) on waves 0-1  ||  P3(m-1) on waves 2-3 ----
      if (t < 128) {
        if ((m < NITER) && ((unsigned)(g0 + m) < (unsigned)DD) && (t < 120))
          P2_BODY(parm * SB_PAR, parm * WPS)
      } else {
        const int s3 = m - 1;
        if ((m >= 1) && (s3 < NITER) &&
            ((unsigned)(g0 + s3) < (unsigned)DD) && (tt < 80)) {
          const int p3 = s3 & 1;
          const float* wrd = &wsum[p3 * WPS + wrOff];
          float4 V0 = *(const float4*)(wrd);
          float4 V1 = *(const float4*)(wrd + 4);
          float4 V2 = *(const float4*)(wrd + 8);
          float4 V3 = *(const float4*)(wrd + 12);
          float4 V4 = *(const float4*)(wrd + 16);
          float4 V5 = *(const float4*)(wrd + 20);
          float v[EXT];
          v[0]=V0.x; v[1]=V0.y; v[2]=V0.z; v[3]=V0.w;
          v[4]=V1.x; v[5]=V1.y; v[6]=V1.z; v[7]=V1.w;
          v[8]=V2.x; v[9]=V2.y; v[10]=V2.z; v[11]=V2.w;
          v[12]=V3.x; v[13]=V3.y; v[14]=V3.z; v[15]=V3.w;
          v[16]=V4.x; v[17]=V4.y; v[18]=V4.z; v[19]=V4.w;
          v[20]=V5.x; v[21]=V5.y; v[22]=V5.z; v[23]=V5.w;
          float hv[TH];
          float sv = ((v[0] + v[1]) + (v[2] + v[3])) +
                     ((v[4] + v[5]) + (v[6] + v[7])) + v[8];
          hv[0] = sv;
#pragma unroll
          for (int h = 1; h < TH; ++h) {
            sv += v[h + 8] - v[h - 1];
            hv[h] = sv;
          }
          float* hq = &hsum[p3 * HPS2 + hwOff];
          *(float4*)&hq[0]  = make_float4(hv[0],  hv[1],  hv[2],  hv[3]);
          *(float4*)&hq[4]  = make_float4(hv[4],  hv[5],  hv[6],  hv[7]);
          *(float4*)&hq[8]  = make_float4(hv[8],  hv[9],  hv[10], hv[11]);
          *(float4*)&hq[12] = make_float4(hv[12], hv[13], hv[14], hv[15]);
        }
      }

      // ---- P4(m-2) on all threads: hsum[(m-2)&1] + ring + cc ----
      const int s4 = m - 2;
      float hv0 = 0.f, hv1 = 0.f, hv2 = 0.f, hv3 = 0.f, hv4 = 0.f;
      if ((m >= 2) && (s4 < NITER) && ((unsigned)(g0 + s4) < (unsigned)DD)) {
        const float* hb = &hsum[(s4 & 1) * HPS2 + hrOff];
        hv0 = hb[0];
        hv1 = hb[HCS2];
        hv2 = hb[2 * HCS2];
        hv3 = hb[3 * HCS2];
        hv4 = hb[4 * HCS2];
      }
      {
        const int rr = (jj + 7) % 9;     // == s4 % 9; compile-time per jj
        run0 += hv0 - ring[rr][0]; ring[rr][0] = hv0;
        run1 += hv1 - ring[rr][1]; ring[rr][1] = hv1;
        run2 += hv2 - ring[rr][2]; ring[rr][2] = hv2;
        run3 += hv3 - ring[rr][3]; ring[rr][3] = hv3;
        run4 += hv4 - ring[rr][4]; ring[rr][4] = hv4;
      }
      if ((s4 >= 8) && (s4 < NITER)) {
        const int d = dc0 + (s4 - 8);
        if (d < DD) {                    // block-uniform tail guard
          float cross = fmaf(-run0 * INV_WS, run1, run4);
          float xv = fmaxf(fmaf(-run0 * INV_WS, run0, run2), EPS);
          float yv = fmaxf(fmaf(-run1 * INV_WS, run1, run3), EPS);
          acc += (cross * cross) * __builtin_amdgcn_rcpf(xv * yv);
        }
      }

      bar_lgkm();   // single barrier per slice
    }
  }

  // ---- block reduction ----
#pragma unroll
  for (int o = 32; o > 0; o >>= 1) acc += __shfl_down(acc, o);
  if ((t & 63) == 0) red[t >> 6] = acc;
  __syncthreads();
  if (t == 0) {
    int bid = (bz * HT + blockIdx.y) * WT + blockIdx.x;
    partials[bid] = (red[0] + red[1]) + (red[2] + red[3]);
  }
}

__global__ void __launch_bounds__(256) k_finalize(
    const float* __restrict__ partials, float* __restrict__ out)
{
  __shared__ double red[256];
  double s = 0.0;
  for (int i = threadIdx.x; i < NBLK; i += 256) s += (double)partials[i];
  red[threadIdx.x] = s;
  __syncthreads();
  for (int o = 128; o > 0; o >>= 1) {
    if (threadIdx.x < o) red[threadIdx.x] += red[threadIdx.x + o];
    __syncthreads();
  }
  if (threadIdx.x == 0) {
    const double Nvox = (double)BB * DD * HH * WW;
    out[0] = (float)(-red[0] / Nvox);
  }
}

extern "C" void kernel_launch(void* const* d_in, const int* in_sizes, int n_in,
                              void* d_out, int out_size, void* d_ws, size_t ws_size,
                              hipStream_t stream) {
  (void)in_sizes; (void)n_in; (void)out_size; (void)ws_size;
  const float* x = (const float*)d_in[0];
  const float* y = (const float*)d_in[1];
  float* out = (float*)d_out;
  float* partials = (float*)d_ws;

  dim3 grid(WT, HT, BB * NCH);
  k_lncc<<<grid, 256, 0, stream>>>(x, y, partials);
  k_finalize<<<1, 256, 0, stream>>>(partials, out);
}